// Round 2
// baseline (635.743 us; speedup 1.0000x reference)
//
#include <hip/hip_runtime.h>
#include <math.h>

#define B_    32
#define H_    32
#define KVH_  8
#define D_    128
#define S_    2048
#define REP   4            // H_/KVH_
#define PAIRS 256          // B_*KVH_
#define SCALE 0.08838834764831845f
#define WTOK  64           // tokens per wave
#define SPLITS (S_/WTOK)   // 32 splits per pair
#define PASSES (WTOK/4)    // 16 passes, 4 tokens each

// k_cache/v_cache: [NUM_BLOCKS, 16, KVH, D]; token row = KVH*D*4 = 4096 B.
// byte offset for (slot, kvh, dim-group g): slot*4096 + kvh*512 + g*16 (< 2^28, fits u32)

struct Tok { float4 k1, k2, v1, v2; int slot, pos; };

__device__ __forceinline__ void load_tok(
    Tok& T, const char* __restrict__ kbase, const char* __restrict__ vbase,
    const int* __restrict__ sm, const int* __restrict__ ps, int idx, unsigned kvg)
{
    T.slot = sm[idx];
    T.pos  = ps[idx];
    const int sc = T.slot < 0 ? 0 : T.slot;
    const unsigned off = (unsigned)sc * 4096u + kvg;
    T.k1 = *(const float4*)(kbase + off);
    T.k2 = *(const float4*)(kbase + off + 256);
    T.v1 = *(const float4*)(vbase + off);
    T.v2 = *(const float4*)(vbase + off + 256);
}

__device__ __forceinline__ void compute_tok(
    const Tok& T, const float* __restrict__ invf,
    const float ql[4][4], const float qh[4][4],
    float acc_lo[4][4], float acc_hi[4][4], float* __restrict__ lsum)
{
    const float m  = (T.slot >= 0) ? 1.f : 0.f;
    const float pf = (float)T.pos;
    const float kx[4] = {T.k1.x, T.k1.y, T.k1.z, T.k1.w};
    const float ky[4] = {T.k2.x, T.k2.y, T.k2.z, T.k2.w};
    float kl[4], kh[4];
    #pragma unroll
    for (int j = 0; j < 4; j++) {
        float sn, cs;
        __sincosf(pf * invf[j], &sn, &cs);
        kl[j] = kx[j] * cs - ky[j] * sn;
        kh[j] = ky[j] * cs + kx[j] * sn;
    }
    float p[4];
    #pragma unroll
    for (int hh = 0; hh < 4; hh++) {
        float t = ql[hh][0] * kl[0];
        t += ql[hh][1] * kl[1];
        t += ql[hh][2] * kl[2];
        t += ql[hh][3] * kl[3];
        t += qh[hh][0] * kh[0];
        t += qh[hh][1] * kh[1];
        t += qh[hh][2] * kh[2];
        t += qh[hh][3] * kh[3];
        p[hh] = t;
    }
    #pragma unroll
    for (int hh = 0; hh < 4; hh++) {
        #pragma unroll
        for (int mm = 1; mm < 16; mm <<= 1)
            p[hh] += __shfl_xor(p[hh], mm);
    }
    const float vx[4] = {T.v1.x, T.v1.y, T.v1.z, T.v1.w};
    const float vy[4] = {T.v2.x, T.v2.y, T.v2.z, T.v2.w};
    #pragma unroll
    for (int hh = 0; hh < 4; hh++) {
        const float w  = __expf(p[hh] * m);  // invalid slot: score->0, w=1 (matches ref)
        const float wm = w * m;              // v masked via wm
        lsum[hh] += w;
        #pragma unroll
        for (int j = 0; j < 4; j++) {
            acc_lo[hh][j] += wm * vx[j];
            acc_hi[hh][j] += wm * vy[j];
        }
    }
}

__global__ __launch_bounds__(256, 4) void pa_main(
    const float* __restrict__ query,
    const float* __restrict__ k_cache,
    const float* __restrict__ v_cache,
    const int*   __restrict__ slot_map,
    const int*   __restrict__ positions,
    float* __restrict__ ws_l,    // [PAIRS*4]
    float* __restrict__ ws_acc)  // [PAIRS*4*128]
{
    const int blk   = blockIdx.x;
    const int pair  = blk >> 3;              // 256 pairs
    const int b     = pair >> 3;
    const int kvh   = pair & 7;
    const int tid   = threadIdx.x;
    const int lane  = tid & 63;
    const int wave  = tid >> 6;
    const int split = ((blk & 7) << 2) + wave;   // 32 splits per pair
    const int g     = lane & 15;
    const int ts    = lane >> 4;

    const char* kbase = (const char*)k_cache;
    const char* vbase = (const char*)v_cache;
    const unsigned kvg = (unsigned)kvh * 512u + (unsigned)g * 16u;
    const int bS  = b * S_;
    const int base = bS + split * WTOK;

    // ---- issue first two token-quad loads immediately ----
    Tok A, Bt;
    load_tok(A,  kbase, vbase, slot_map, positions, base + 0 + ts, kvg);
    load_tok(Bt, kbase, vbase, slot_map, positions, base + 4 + ts, kvg);

    // ---- inv_freq (one-time; 4 double exp, no double trig anywhere) ----
    double invf_d[4];
    float  invf[4];
    #pragma unroll
    for (int j = 0; j < 4; j++) {
        invf_d[j] = exp(-(double)(4 * g + j) * (9.2103403719761836 / 64.0));
        invf[j]   = (float)invf_d[j];
    }

    // ---- q rope (trig hoisted out of head loop; f64 mults + rint reduction only) ----
    const int posq = positions[bS + (S_ - 1)];
    float csq[4], snq[4];
    #pragma unroll
    for (int j = 0; j < 4; j++) {
        const double rev  = (double)posq * invf_d[j] * 0.15915494309189535;  // phase / 2pi
        const double frac = rev - __builtin_rint(rev);
        __sincosf((float)frac * 6.283185307179586f, &snq[j], &csq[j]);
    }
    float ql[4][4], qh[4][4];
    #pragma unroll
    for (int hh = 0; hh < REP; hh++) {
        const float4* qb = (const float4*)(query + (size_t)(b * H_ + kvh * REP + hh) * D_);
        const float4 a = qb[g];
        const float4 c = qb[16 + g];
        const float al[4] = {a.x, a.y, a.z, a.w};
        const float ah[4] = {c.x, c.y, c.z, c.w};
        #pragma unroll
        for (int j = 0; j < 4; j++) {
            ql[hh][j] = (al[j] * csq[j] - ah[j] * snq[j]) * SCALE;
            qh[hh][j] = (ah[j] * csq[j] + al[j] * snq[j]) * SCALE;
        }
    }

    float acc_lo[4][4] = {};
    float acc_hi[4][4] = {};
    float lsum[4] = {0.f, 0.f, 0.f, 0.f};

    // ---- unroll-2 pipeline: loads land directly in fixed buffers, no rotation copies ----
    for (int i = 0; i < PASSES; i += 2) {
        compute_tok(A, invf, ql, qh, acc_lo, acc_hi, lsum);
        if (i + 2 < PASSES)
            load_tok(A, kbase, vbase, slot_map, positions, base + (i + 2) * 4 + ts, kvg);
        compute_tok(Bt, invf, ql, qh, acc_lo, acc_hi, lsum);
        if (i + 3 < PASSES)
            load_tok(Bt, kbase, vbase, slot_map, positions, base + (i + 3) * 4 + ts, kvg);
    }

    // ---- merge the 4 token-slots within the wave ----
    #pragma unroll
    for (int hh = 0; hh < 4; hh++) {
        lsum[hh] += __shfl_xor(lsum[hh], 16);
        lsum[hh] += __shfl_xor(lsum[hh], 32);
        #pragma unroll
        for (int j = 0; j < 4; j++) {
            acc_lo[hh][j] += __shfl_xor(acc_lo[hh][j], 16);
            acc_lo[hh][j] += __shfl_xor(acc_lo[hh][j], 32);
            acc_hi[hh][j] += __shfl_xor(acc_hi[hh][j], 16);
            acc_hi[hh][j] += __shfl_xor(acc_hi[hh][j], 32);
        }
    }

    // ---- device-scope atomic merge (sums are rescale-free; no inter-wave coupling) ----
    if (lane < 16) {
        #pragma unroll
        for (int hh = 0; hh < 4; hh++) {
            float* dst = ws_acc + ((size_t)(pair * 4 + hh)) * 128;
            #pragma unroll
            for (int j = 0; j < 4; j++) {
                atomicAdd(dst + 4 * g + j,      acc_lo[hh][j]);
                atomicAdd(dst + 64 + 4 * g + j, acc_hi[hh][j]);
            }
        }
    }
    if (lane == 0) {
        #pragma unroll
        for (int hh = 0; hh < 4; hh++)
            atomicAdd(ws_l + pair * 4 + hh, lsum[hh]);
    }
}

__global__ __launch_bounds__(512) void pa_div(
    const float* __restrict__ ws_l,
    const float* __restrict__ ws_acc,
    float* __restrict__ out)
{
    const int pair = blockIdx.x;
    const int hh = threadIdx.x >> 7;
    const int d  = threadIdx.x & 127;
    const float a  = ws_acc[((size_t)(pair * 4 + hh)) * 128 + d];
    const float lt = ws_l[pair * 4 + hh];
    out[((size_t)((pair >> 3) * H_ + (pair & 7) * REP + hh)) * D_ + d] = a / lt;
}

extern "C" void kernel_launch(void* const* d_in, const int* in_sizes, int n_in,
                              void* d_out, int out_size, void* d_ws, size_t ws_size,
                              hipStream_t stream) {
    const float* query = (const float*)d_in[0];
    const float* kc    = (const float*)d_in[1];
    const float* vc    = (const float*)d_in[2];
    const int*   sm    = (const int*)d_in[3];
    const int*   pos   = (const int*)d_in[4];
    float* out = (float*)d_out;

    float* ws_l   = (float*)d_ws;                 // PAIRS*4 floats
    float* ws_acc = ws_l + PAIRS * 4;             // PAIRS*4*128 floats
    const size_t zero_bytes = (size_t)PAIRS * 4 * (1 + 128) * sizeof(float); // 528 KB

    hipMemsetAsync(d_ws, 0, zero_bytes, stream);
    pa_main<<<dim3(PAIRS * (SPLITS / 4)), dim3(256), 0, stream>>>(
        query, kc, vc, sm, pos, ws_l, ws_acc);
    pa_div<<<dim3(PAIRS), dim3(512), 0, stream>>>(ws_l, ws_acc, out);
}